// Round 7
// baseline (348.414 us; speedup 1.0000x reference)
//
#include <hip/hip_runtime.h>
#include <hip/hip_bf16.h>

#define K_DIM 4096
#define N_DIM 12288
#define B_DIM 64
#define G_DIM 64          // K / 64 groups
#define R_DIM 32
#define NT_DIM 768        // N / 16 n-tiles
#define GPB 16            // groups per main block (K-split x4)

typedef int v4i __attribute__((ext_vector_type(4)));

__device__ __forceinline__ int pack4(const v4i a) {
    return (a.x & 255) | ((a.y & 255) << 8) | ((a.z & 255) << 16) | (a.w << 24);
}

// ---------------------------------------------------------------------------
// Kernel 1: fused quantize + lora-down partial (R6 version — unchanged,
// proven in the 297.7 us baseline).
// ---------------------------------------------------------------------------
__global__ __launch_bounds__(256) void quant_lora_kernel(
    const float* __restrict__ x, const float* __restrict__ smooth,
    const float* __restrict__ ld, char* __restrict__ xq_p,
    float* __restrict__ ascale, float* __restrict__ t_part) {
    const int b = blockIdx.x >> 4;
    const int kc = blockIdx.x & 15;
    const int tid = threadIdx.x;
    const int k = kc * 256 + tid;

    __shared__ float sx[256];
    __shared__ float red[256];

    const float xd = x[b * K_DIM + k] / smooth[k];
    sx[tid] = xd;

    // --- quant (wave == group) ---
    const int lane = tid & 63;
    float a = fabsf(xd);
    #pragma unroll
    for (int off = 32; off; off >>= 1) a = fmaxf(a, __shfl_xor(a, off));
    const float as = fmaxf(a / 7.0f, 1e-8f);
    float q = rintf(xd / as);
    q = fminf(fmaxf(q, -8.0f), 7.0f);
    const int g = kc * 4 + (tid >> 6);
    const int bt = b >> 4, b15 = b & 15;
    const int quad = lane >> 4, kin = lane & 15;
    xq_p[((((size_t)bt * G_DIM + g) * 64) + quad * 16 + b15) * 16 + kin] = (char)(int)q;
    if (lane == 0) ascale[b * G_DIM + g] = as;
    __syncthreads();

    // --- lora-down partial over this 256-k chunk ---
    const int r = tid & 31, c = tid >> 5;     // c = 0..7
    const int kb = kc * 256 + c * 32;
    float acc = 0.f;
    #pragma unroll 8
    for (int kk = 0; kk < 32; ++kk)
        acc += sx[c * 32 + kk] * ld[(size_t)(kb + kk) * R_DIM + r];
    red[tid] = acc;
    __syncthreads();
    if (tid < 32) {
        float s = 0.f;
        #pragma unroll
        for (int c2 = 0; c2 < 8; ++c2) s += red[c2 * 32 + tid];
        t_part[kc * (B_DIM * R_DIM) + b * R_DIM + tid] = s;
    }
}

// ---------------------------------------------------------------------------
// Kernel 1b (R13 new): reduce t_part's 16 k-slices -> t[64][32]. Tiny (2048
// outputs, grid 8). Removes the 16-slice re-read from the hot main kernel.
// ---------------------------------------------------------------------------
__global__ __launch_bounds__(256) void treduce_kernel(
    const float* __restrict__ t_part, float* __restrict__ t) {
    const int i = blockIdx.x * 256 + threadIdx.x;   // 0..2047
    float s = 0.f;
    #pragma unroll
    for (int kc = 0; kc < 16; ++kc) s += t_part[kc * (B_DIM * R_DIM) + i];
    t[i] = s;
}

// ---------------------------------------------------------------------------
// Kernel 2: main GEMM — R13: K-SPLIT x4 for occupancy (TLP instead of ILP).
// R10/R11/R12 post-mortem: per-wave pipelining is unobtainable in HIP source
// (compiler collapses named stages, R11 VGPR=64; forced asm staging faults,
// R12). But the depth-1 kernel at 12 waves/CU (25% occupancy) ran 127 us —
// both candidate bottlenecks (VMEM latency, scattered-load issue cost)
// scale with resident waves. So: block = 16 n-rows x 16 GROUPS (quarter-K),
// grid = 768 x 4 = 3072 = 12 rounds of 8 blocks/CU.
//   occupancy gates: VGPR<=64 (R10 body compiled at 52; lora epilogue and
//   its lu[8]=32 regs are gone), LDS 5.4 KB, 32 waves/CU cap -> 8 blocks/CU.
// Partials to psum[kc][b][n] (disjoint coalesced stores; every entry
// written -> no zero-init; no atomics -> deterministic). Same proven R10
// math and fragment mapping; g runs g0..g0+15.
// ---------------------------------------------------------------------------
__global__ __launch_bounds__(256) void main_ksplit_kernel(
    const int* __restrict__ qw, const float* __restrict__ wscales,
    const v4i* __restrict__ xq_p, const float* __restrict__ ascale,
    float* __restrict__ psum) {
    __shared__ float s_ws[GPB * 16];        // [gl][j]  1 KB
    __shared__ float s_as[GPB * 68];        // [gl][b]  4.25 KB (pad 68)

    const int bid = blockIdx.x;
    const int nt = bid >> 2, kc = bid & 3;
    const int n0 = nt * 16, g0 = kc * GPB;
    const int tid = threadIdx.x;

    // stage scales for this block's 16 groups
    if (tid < GPB * 16)
        s_ws[tid] = wscales[(g0 + (tid >> 4)) * N_DIM + n0 + (tid & 15)];
    #pragma unroll
    for (int i = tid; i < B_DIM * GPB; i += 256) {
        const int b = i & 63, gl = i >> 6;
        s_as[gl * 68 + b] = ascale[b * G_DIM + g0 + gl];
    }
    __syncthreads();                        // the ONLY block barrier

    const int w = tid >> 6, lane = tid & 63;
    const int col = lane & 15, quad = lane >> 4;

    float facc[4] = {0.f, 0.f, 0.f, 0.f};
    const v4i zero = {0, 0, 0, 0};
    const v4i* xbase = xq_p + (size_t)w * G_DIM * 64 + lane;          // [w][g][lane]
    const int* bsrc = qw + (size_t)(n0 + col) * K_DIM + quad * 16;    // per-lane row

    #pragma unroll 2
    for (int gl = 0; gl < GPB; ++gl) {
        const int g = g0 + gl;
        const int* p = bsrc + g * 64;
        const v4i a0 = *(const v4i*)(p);
        const v4i a1 = *(const v4i*)(p + 4);
        const v4i a2 = *(const v4i*)(p + 8);
        const v4i a3 = *(const v4i*)(p + 12);
        v4i bq;
        bq.x = pack4(a0); bq.y = pack4(a1); bq.z = pack4(a2); bq.w = pack4(a3);
        const v4i xa = xbase[(size_t)g * 64];
        const v4i d = __builtin_amdgcn_mfma_i32_16x16x64_i8(xa, bq, zero, 0, 0, 0);
        const float wsc = s_ws[gl * 16 + col];
        const float4 as4 = *(const float4*)&s_as[gl * 68 + w * 16 + quad * 4];
        facc[0] = fmaf(as4.x * wsc, (float)d[0], facc[0]);
        facc[1] = fmaf(as4.y * wsc, (float)d[1], facc[1]);
        facc[2] = fmaf(as4.z * wsc, (float)d[2], facc[2]);
        facc[3] = fmaf(as4.w * wsc, (float)d[3], facc[3]);
    }

    // partial store: psum[kc][b][n0+col] — coalesced over col
    float* pp = psum + (size_t)kc * B_DIM * N_DIM;
    #pragma unroll
    for (int r = 0; r < 4; ++r) {
        const int b = w * 16 + quad * 4 + r;
        pp[(size_t)b * N_DIM + n0 + col] = facc[r];
    }
}

// ---------------------------------------------------------------------------
// Kernel 3 (R13 new): final combine — out = sum_kc psum + bias + t @ lu^T.
// Grid 192 blocks x 64 n-cols; thread (bq=tid>>6, n=n0+(tid&63)) covers 16
// b-rows. All reads/writes coalesced over n; t (8 KB) staged in LDS.
// Traffic: 12 MB psum + ~6 MB lu + 3 MB out ≈ 3-4 us.
// ---------------------------------------------------------------------------
__global__ __launch_bounds__(256) void final_kernel(
    const float* __restrict__ psum, const float* __restrict__ t,
    const float* __restrict__ lora_up, const float* __restrict__ bias,
    float* __restrict__ out) {
    __shared__ float s_t[B_DIM * R_DIM];    // 8 KB
    const int n0 = blockIdx.x * 64;
    const int tid = threadIdx.x;
    for (int i = tid; i < B_DIM * R_DIM; i += 256) s_t[i] = t[i];
    __syncthreads();

    const int n = n0 + (tid & 63);
    const int bq = tid >> 6;                // 0..3 -> 16 b-rows each
    float4 lu[8];
    {
        const float4* lp = (const float4*)(lora_up + (size_t)n * R_DIM);
        #pragma unroll
        for (int i = 0; i < 8; ++i) lu[i] = lp[i];
    }
    const float bs = bias[n];
    #pragma unroll 4
    for (int r = 0; r < 16; ++r) {
        const int b = bq * 16 + r;
        float acc = bs;
        #pragma unroll
        for (int kc = 0; kc < 4; ++kc)
            acc += psum[((size_t)kc * B_DIM + b) * N_DIM + n];
        #pragma unroll
        for (int r2 = 0; r2 < 8; ++r2) {
            const float4 tv = *(const float4*)&s_t[b * R_DIM + r2 * 4];
            acc += tv.x * lu[r2].x + tv.y * lu[r2].y +
                   tv.z * lu[r2].z + tv.w * lu[r2].w;
        }
        out[(size_t)b * N_DIM + n] = acc;
    }
}

// ---------------------------------------------------------------------------
extern "C" void kernel_launch(void* const* d_in, const int* in_sizes, int n_in,
                              void* d_out, int out_size, void* d_ws, size_t ws_size,
                              hipStream_t stream) {
    const float* x         = (const float*)d_in[0];
    const int*   q_w       = (const int*)d_in[1];
    const float* wscales   = (const float*)d_in[2];
    const float* lora_down = (const float*)d_in[3];
    const float* lora_up   = (const float*)d_in[4];
    const float* smooth    = (const float*)d_in[5];
    const float* bias      = (const float*)d_in[6];
    float* out = (float*)d_out;

    char*  xq     = (char*)d_ws;                            // 256 KB packed acts
    float* ascale = (float*)((char*)d_ws + 262144);         // 16 KB
    float* t_part = (float*)((char*)d_ws + 262144 + 16384); // 128 KB (16 slices)
    float* t      = (float*)((char*)d_ws + 409600);         // 8 KB reduced t
    float* psum   = (float*)((char*)d_ws + 417792);         // 12 MB partials

    quant_lora_kernel<<<B_DIM * 16, 256, 0, stream>>>(x, smooth, lora_down,
                                                      xq, ascale, t_part);
    treduce_kernel<<<8, 256, 0, stream>>>(t_part, t);
    main_ksplit_kernel<<<NT_DIM * 4, 256, 0, stream>>>(q_w, wscales,
                                                       (const v4i*)xq, ascale,
                                                       psum);
    final_kernel<<<N_DIM / 64, 256, 0, stream>>>(psum, t, lora_up, bias, out);
}

// Round 8
// 316.942 us; speedup vs baseline: 1.0993x; 1.0993x over previous
//
#include <hip/hip_runtime.h>
#include <hip/hip_bf16.h>

#define K_DIM 4096
#define N_DIM 12288
#define B_DIM 64
#define G_DIM 64          // K / 64 groups
#define R_DIM 32
#define NT_DIM 768        // N / 16 n-tiles
#define GPB 16            // groups per main block (K-split x4)

typedef int v4i __attribute__((ext_vector_type(4)));

__device__ __forceinline__ int pack4(const v4i a) {
    return (a.x & 255) | ((a.y & 255) << 8) | ((a.z & 255) << 16) | (a.w << 24);
}

// ---------------------------------------------------------------------------
// Kernel 1: fused quantize + lora-down partial (unchanged, proven).
// ---------------------------------------------------------------------------
__global__ __launch_bounds__(256) void quant_lora_kernel(
    const float* __restrict__ x, const float* __restrict__ smooth,
    const float* __restrict__ ld, char* __restrict__ xq_p,
    float* __restrict__ ascale, float* __restrict__ t_part) {
    const int b = blockIdx.x >> 4;
    const int kc = blockIdx.x & 15;
    const int tid = threadIdx.x;
    const int k = kc * 256 + tid;

    __shared__ float sx[256];
    __shared__ float red[256];

    const float xd = x[b * K_DIM + k] / smooth[k];
    sx[tid] = xd;

    const int lane = tid & 63;
    float a = fabsf(xd);
    #pragma unroll
    for (int off = 32; off; off >>= 1) a = fmaxf(a, __shfl_xor(a, off));
    const float as = fmaxf(a / 7.0f, 1e-8f);
    float q = rintf(xd / as);
    q = fminf(fmaxf(q, -8.0f), 7.0f);
    const int g = kc * 4 + (tid >> 6);
    const int bt = b >> 4, b15 = b & 15;
    const int quad = lane >> 4, kin = lane & 15;
    xq_p[((((size_t)bt * G_DIM + g) * 64) + quad * 16 + b15) * 16 + kin] = (char)(int)q;
    if (lane == 0) ascale[b * G_DIM + g] = as;
    __syncthreads();

    const int r = tid & 31, c = tid >> 5;
    const int kb = kc * 256 + c * 32;
    float acc = 0.f;
    #pragma unroll 8
    for (int kk = 0; kk < 32; ++kk)
        acc += sx[c * 32 + kk] * ld[(size_t)(kb + kk) * R_DIM + r];
    red[tid] = acc;
    __syncthreads();
    if (tid < 32) {
        float s = 0.f;
        #pragma unroll
        for (int c2 = 0; c2 < 8; ++c2) s += red[c2 * 32 + tid];
        t_part[kc * (B_DIM * R_DIM) + b * R_DIM + tid] = s;
    }
}

// ---------------------------------------------------------------------------
// Kernel 1b: reduce t_part's 16 k-slices -> t[64][32] (unchanged).
// ---------------------------------------------------------------------------
__global__ __launch_bounds__(256) void treduce_kernel(
    const float* __restrict__ t_part, float* __restrict__ t) {
    const int i = blockIdx.x * 256 + threadIdx.x;
    float s = 0.f;
    #pragma unroll
    for (int kc = 0; kc < 16; ++kc) s += t_part[kc * (B_DIM * R_DIM) + i];
    t[i] = s;
}

// ---------------------------------------------------------------------------
// Kernel 2: main GEMM — R14: TRANSACTION-OPTIMAL weight loads + per-wave
// n-tile ownership + in-wave LDS gather.
// R13 post-mortem: occupancy 25->52% with dur UNCHANGED (120 us) -> not
// latency-bound. Root cause (closed-form): the R10/R13 weight load pattern
// touches 64 distinct 64B lines per dwordx4 instr (16 B used each) -> 272
// L1 line-lookups/group/wave, x4 wave redundancy -> 209k cy/CU = 87 us of
// pure L1 tag bandwidth. Neither ILP nor TLP can fix a tag-rate cap.
// R14: (a) wave owns ONE n-tile (block = 4 waves = 4 n-tiles, kc quarter-K
// kept; grid 768) -> zero inter-wave weight redundancy; (b) weight loads
// instr j: lane l -> row l>>2, dwords j*16+(l&3)*4 -> 16 full lines/instr
// (minimum); (c) lane packs int32->int8 (pack4), ds_writes 4 dwords into a
// PRIVATE per-wave 1 KB LDS buffer (chunk-XOR swizzle slot=j^((r>>1)&3)),
// then ds_read_b128 in MFMA fragment order. Same-wave LDS write->read:
// compiler-ordered lgkmcnt, NO barriers, no cross-wave hazards (the safe
// class — unlike R8/R12). Lookups/CU: 209k -> ~25k cy; new floor = HBM
// (201 MB weights) + latency slop.
// Wave computes all 4 b-tiles: 4 MFMAs/group, facc[4][4].
// ---------------------------------------------------------------------------
__global__ __launch_bounds__(256) void main_ksplit_kernel(
    const int* __restrict__ qw, const float* __restrict__ wscales,
    const v4i* __restrict__ xq_p, const float* __restrict__ ascale,
    float* __restrict__ psum) {
    __shared__ float s_ws[4 * GPB * 16];    // [w][gl][col]   4 KB
    __shared__ float s_as[GPB * 68];        // [gl][b]        4.25 KB (pad 68)
    __shared__ int   s_pw[4][256];          // per-wave packed group buffer 4 KB

    const int bid = blockIdx.x;
    const int ntb = bid >> 2, kc = bid & 3;
    const int g0 = kc * GPB;
    const int tid = threadIdx.x;

    // stage wscales: wave w' needs [g0+gl][ (ntb*4+w')*16 + c ]
    #pragma unroll
    for (int i = tid; i < 4 * GPB * 16; i += 256) {
        const int w2 = i >> 8, gl = (i >> 4) & 15, c = i & 15;
        s_ws[i] = wscales[(g0 + gl) * N_DIM + (ntb * 4 + w2) * 16 + c];
    }
    // stage ascale for this kc's 16 groups, all 64 b
    #pragma unroll
    for (int i = tid; i < B_DIM * GPB; i += 256) {
        const int b = i & 63, gl = i >> 6;
        s_as[gl * 68 + b] = ascale[b * G_DIM + g0 + gl];
    }
    __syncthreads();                        // the ONLY block barrier

    const int w = tid >> 6, lane = tid & 63;
    const int nt = ntb * 4 + w;
    const int n0 = nt * 16;
    const int col = lane & 15, quad = lane >> 4;

    // weight-load role: row r = lane>>2 (of this wave's 16 rows), c = lane&3
    const int lr = lane >> 2, lc = lane & 3;
    const int lswz = (lr >> 1) & 3;                       // chunk swizzle key
    const int* wsrc = qw + (size_t)(n0 + lr) * K_DIM + lc * 4;  // + g*64 + j*16

    // MFMA-read role: row col, chunk quad (swizzled by col's key)
    const int rswz = (col >> 1) & 3;
    int* const mywr = &s_pw[w][lr * 16 + lc];             // + slot*4
    const int* const myrd = &s_pw[w][col * 16 + (quad ^ rswz) * 4];

    float facc[4][4];
    #pragma unroll
    for (int i = 0; i < 4; ++i)
        #pragma unroll
        for (int j = 0; j < 4; ++j) facc[i][j] = 0.f;

    const v4i zero = {0, 0, 0, 0};
    const v4i* xgbase = xq_p + (size_t)g0 * 64 + lane;    // + bt*G*64 + gl*64

    #pragma unroll 2
    for (int gl = 0; gl < GPB; ++gl) {
        // --- transaction-optimal weight load: 4 instr x 16 full lines ---
        const int* p = wsrc + (g0 + gl) * 64;
        const v4i q0 = *(const v4i*)(p);
        const v4i q1 = *(const v4i*)(p + 16);
        const v4i q2 = *(const v4i*)(p + 32);
        const v4i q3 = *(const v4i*)(p + 48);
        // --- pack + in-wave LDS scatter (slot = j ^ swz(row)) ---
        mywr[((0 ^ lswz) * 4)] = pack4(q0);
        mywr[((1 ^ lswz) * 4)] = pack4(q1);
        mywr[((2 ^ lswz) * 4)] = pack4(q2);
        mywr[((3 ^ lswz) * 4)] = pack4(q3);
        // --- gather this lane's MFMA B-fragment ---
        const v4i bq = *(const v4i*)myrd;
        // --- 4 b-tiles ---
        const float wsc = s_ws[(w * GPB + gl) * 16 + col];
        #pragma unroll
        for (int bt = 0; bt < 4; ++bt) {
            const v4i xa = xgbase[((size_t)bt * G_DIM + gl) * 64];
            const v4i d =
                __builtin_amdgcn_mfma_i32_16x16x64_i8(xa, bq, zero, 0, 0, 0);
            const float4 as4 =
                *(const float4*)&s_as[gl * 68 + bt * 16 + quad * 4];
            facc[bt][0] = fmaf(as4.x * wsc, (float)d[0], facc[bt][0]);
            facc[bt][1] = fmaf(as4.y * wsc, (float)d[1], facc[bt][1]);
            facc[bt][2] = fmaf(as4.z * wsc, (float)d[2], facc[bt][2]);
            facc[bt][3] = fmaf(as4.w * wsc, (float)d[3], facc[bt][3]);
        }
    }

    // partial store: psum[kc][b][n0+col]
    float* pp = psum + (size_t)kc * B_DIM * N_DIM;
    #pragma unroll
    for (int bt = 0; bt < 4; ++bt)
        #pragma unroll
        for (int r = 0; r < 4; ++r) {
            const int b = bt * 16 + quad * 4 + r;
            pp[(size_t)b * N_DIM + n0 + col] = facc[bt][r];
        }
}

// ---------------------------------------------------------------------------
// Kernel 3: final combine — out = sum_kc psum + bias + t @ lu^T (unchanged).
// ---------------------------------------------------------------------------
__global__ __launch_bounds__(256) void final_kernel(
    const float* __restrict__ psum, const float* __restrict__ t,
    const float* __restrict__ lora_up, const float* __restrict__ bias,
    float* __restrict__ out) {
    __shared__ float s_t[B_DIM * R_DIM];    // 8 KB
    const int n0 = blockIdx.x * 64;
    const int tid = threadIdx.x;
    for (int i = tid; i < B_DIM * R_DIM; i += 256) s_t[i] = t[i];
    __syncthreads();

    const int n = n0 + (tid & 63);
    const int bq = tid >> 6;
    float4 lu[8];
    {
        const float4* lp = (const float4*)(lora_up + (size_t)n * R_DIM);
        #pragma unroll
        for (int i = 0; i < 8; ++i) lu[i] = lp[i];
    }
    const float bs = bias[n];
    #pragma unroll 4
    for (int r = 0; r < 16; ++r) {
        const int b = bq * 16 + r;
        float acc = bs;
        #pragma unroll
        for (int kc = 0; kc < 4; ++kc)
            acc += psum[((size_t)kc * B_DIM + b) * N_DIM + n];
        #pragma unroll
        for (int r2 = 0; r2 < 8; ++r2) {
            const float4 tv = *(const float4*)&s_t[b * R_DIM + r2 * 4];
            acc += tv.x * lu[r2].x + tv.y * lu[r2].y +
                   tv.z * lu[r2].z + tv.w * lu[r2].w;
        }
        out[(size_t)b * N_DIM + n] = acc;
    }
}

// ---------------------------------------------------------------------------
extern "C" void kernel_launch(void* const* d_in, const int* in_sizes, int n_in,
                              void* d_out, int out_size, void* d_ws, size_t ws_size,
                              hipStream_t stream) {
    const float* x         = (const float*)d_in[0];
    const int*   q_w       = (const int*)d_in[1];
    const float* wscales   = (const float*)d_in[2];
    const float* lora_down = (const float*)d_in[3];
    const float* lora_up   = (const float*)d_in[4];
    const float* smooth    = (const float*)d_in[5];
    const float* bias      = (const float*)d_in[6];
    float* out = (float*)d_out;

    char*  xq     = (char*)d_ws;                            // 256 KB packed acts
    float* ascale = (float*)((char*)d_ws + 262144);         // 16 KB
    float* t_part = (float*)((char*)d_ws + 262144 + 16384); // 128 KB (16 slices)
    float* t      = (float*)((char*)d_ws + 409600);         // 8 KB reduced t
    float* psum   = (float*)((char*)d_ws + 417792);         // 12 MB partials

    quant_lora_kernel<<<B_DIM * 16, 256, 0, stream>>>(x, smooth, lora_down,
                                                      xq, ascale, t_part);
    treduce_kernel<<<8, 256, 0, stream>>>(t_part, t);
    main_ksplit_kernel<<<NT_DIM, 256, 0, stream>>>(q_w, wscales,
                                                   (const v4i*)xq, ascale,
                                                   psum);
    final_kernel<<<N_DIM / 64, 256, 0, stream>>>(psum, t, lora_up, bias, out);
}